// Round 9
// baseline (2848.102 us; speedup 1.0000x reference)
//
#include <hip/hip_runtime.h>
#include <math.h>

// ---- problem constants ----
#define BB   8
#define TT   5
#define NN   2048
#define FIN  64
#define EE   32768
#define DD   256
#define HH   8
#define FFD  2048
#define NCLS 10
#define GG   (BB*TT)        // 40 graphs
#define BN   (BB*NN)        // 16384
#define NM   (GG*NN)        // 81920 rows (= TT*BN)
#define NE   ((long)GG*EE)  // 1310720 edges

typedef __attribute__((ext_vector_type(8))) short short8;
typedef __attribute__((ext_vector_type(4))) float f32x4;

// ---- bf16 helpers (RNE) ----
__device__ __forceinline__ unsigned short f2b(float f) {
    unsigned u = __float_as_uint(f);
    u = (u + 0x7fffu + ((u >> 16) & 1u)) >> 16;
    return (unsigned short)u;
}
__device__ __forceinline__ float b2f(unsigned short b) {
    return __uint_as_float(((unsigned)b) << 16);
}

// async global->LDS, 16B per lane (dest must be wave-uniform base + lane*16)
__device__ __forceinline__ void gload_lds16(const void* g, void* l) {
    __builtin_amdgcn_global_load_lds(
        (__attribute__((address_space(1))) void*)g,
        (__attribute__((address_space(3))) void*)l, 16, 0, 0);
}

// =====================================================================
// Weight transpose+convert: in fp32 [K][N] row-major -> out bf16 [N][K]
// =====================================================================
__global__ void wtrans(const float* __restrict__ in, unsigned short* __restrict__ out,
                       int K, int N) {
    __shared__ float t[32][33];
    const int n0 = blockIdx.x * 32, k0 = blockIdx.y * 32;
    const int tx = threadIdx.x, ty = threadIdx.y;
    for (int i = ty; i < 32; i += 8) t[i][tx] = in[(long)(k0 + i) * N + n0 + tx];
    __syncthreads();
    for (int i = ty; i < 32; i += 8)
        out[(long)(n0 + i) * K + k0 + tx] = f2b(t[tx][i]);
}

// fp32 -> bf16 elementwise (n4 float4 groups)
__global__ void xconvert(const float* __restrict__ in, unsigned short* __restrict__ out, long n4) {
    long gid = (long)blockIdx.x * blockDim.x + threadIdx.x;
    if (gid >= n4) return;
    float4 v = ((const float4*)in)[gid];
    ushort4 o;
    o.x = f2b(v.x); o.y = f2b(v.y); o.z = f2b(v.z); o.w = f2b(v.w);
    ((ushort4*)out)[gid] = o;
}

// pack 3 bias vectors of 256 into one 768 buffer
__global__ void pack3(const float* __restrict__ a, const float* __restrict__ b,
                      const float* __restrict__ c, float* __restrict__ o) {
    int i = threadIdx.x;
    o[i] = a[i]; o[256 + i] = b[i]; o[512 + i] = c[i];
}

// =====================================================================
// bf16 MFMA GEMM (m97 structure + XCD swizzle):
// C[M x N] = A[M x K] @ W[K x N] + bias
// =====================================================================
template <bool RELU, bool OUTBF>
__global__ __launch_bounds__(256) void gemm_mfma(
    const unsigned short* __restrict__ A, int lda,
    const unsigned short* __restrict__ WT,
    const float* __restrict__ bias,
    void* __restrict__ Cv, int ldc, int K)
{
    __shared__ unsigned short As[128 * 32];
    __shared__ unsigned short Bs[128 * 32];
    const int tid = threadIdx.x;
    const int wid = tid >> 6, lane = tid & 63;
    const int wm = wid >> 1, wn = wid & 1;
    const int gx = gridDim.x, gy = gridDim.y;
    int bx = blockIdx.x, by = blockIdx.y;
    if ((gx & 7) == 0) {
        const int lbid = bx + gx * by;
        const int xcd = lbid & 7;
        const int i = lbid >> 3;
        const int CX = gx >> 3;
        bx = xcd * CX + i / gy;
        by = i - (i / gy) * gy;
    }
    const long row0 = (long)bx * 128;
    const long col0 = (long)by * 128;
    const int srow = tid >> 2;
    const int scol = (tid & 3) * 8;
    const int kb = (lane >> 4) * 8;
    const int fr = lane & 15;
    f32x4 acc[4][4] = {};
    const unsigned short* Ag = &A[(row0 + srow) * (long)lda + scol];
    const unsigned short* Bg = &WT[(col0 + srow) * (long)K + scol];
    unsigned short* Al = &As[srow * 32 + scol];
    unsigned short* Bl = &Bs[srow * 32 + scol];
    for (int k0 = 0; k0 < K; k0 += 32) {
        __syncthreads();
        gload_lds16(Ag + k0, Al);
        gload_lds16(Ag + (long)64 * lda + k0, Al + 64 * 32);
        gload_lds16(Bg + k0, Bl);
        gload_lds16(Bg + (long)64 * K + k0, Bl + 64 * 32);
        __syncthreads();
        short8 af[4], bfr[4];
#pragma unroll
        for (int mf = 0; mf < 4; ++mf)
            af[mf] = *(const short8*)&As[(wm * 64 + mf * 16 + fr) * 32 + kb];
#pragma unroll
        for (int nf = 0; nf < 4; ++nf)
            bfr[nf] = *(const short8*)&Bs[(wn * 64 + nf * 16 + fr) * 32 + kb];
#pragma unroll
        for (int mf = 0; mf < 4; ++mf)
#pragma unroll
            for (int nf = 0; nf < 4; ++nf)
                acc[mf][nf] = __builtin_amdgcn_mfma_f32_16x16x32_bf16(
                    af[mf], bfr[nf], acc[mf][nf], 0, 0, 0);
    }
    const int fq = lane >> 4;
#pragma unroll
    for (int nf = 0; nf < 4; ++nf) {
        const long col = col0 + wn * 64 + nf * 16 + fr;
        const float bv = bias[col];
#pragma unroll
        for (int mf = 0; mf < 4; ++mf) {
#pragma unroll
            for (int i = 0; i < 4; ++i) {
                const long r = row0 + wm * 64 + mf * 16 + fq * 4 + i;
                float vv = acc[mf][nf][i] + bv;
                if (RELU) vv = fmaxf(vv, 0.f);
                if (OUTBF) ((unsigned short*)Cv)[r * ldc + col] = f2b(vv);
                else       ((float*)Cv)[r * ldc + col] = vv;
            }
        }
    }
}

// =====================================================================
// Fused FFN v2: C[64 x 256](ldc,bf16) = relu(A[64x256] @ W1 + b1) @ W2 + b2
// W fragments read DIRECTLY from global (L2-resident); LDS only for the
// A-tile (32KB, XOR-swizzled via pre-swizzled gload source) and the H-tile
// (18KB, +32B padded rows, packed b32 writes via shfl pair-exchange).
// 50KB LDS -> 3 blocks/CU; 2 barriers per 128-hidden chunk.
// =====================================================================
__global__ __launch_bounds__(256) void ffn_fused(
    const unsigned short* __restrict__ A,
    const unsigned short* __restrict__ w1t,
    const unsigned short* __restrict__ w2t,
    const float* __restrict__ b1, const float* __restrict__ b2,
    unsigned short* __restrict__ C, int ldc)
{
    __shared__ unsigned short As[64 * 256];
    __shared__ unsigned short Hl[64 * 144];   // 288B rows (16B aligned, pad kills pow2)
    const int tid = threadIdx.x;
    const int wn = tid >> 6, lane = tid & 63;
    const int fr = lane & 15, q = lane >> 4;
    const int kb2 = q * 16;                   // byte offset of k-subgroup
    const int nb = gridDim.x;
    const int bid = ((nb & 7) == 0) ? (blockIdx.x & 7) * (nb >> 3) + (blockIdx.x >> 3)
                                    : blockIdx.x;
    const long M0 = (long)bid * 64;
    // stage A-tile once (linear LDS dest, pre-swizzled global source)
#pragma unroll
    for (int c = 0; c < 8; ++c) {
        int row = c * 8 + (tid >> 5);
        int chunk = (tid & 31) ^ (row & 7);
        gload_lds16(A + (M0 + row) * 256 + chunk * 8, As + c * 2048 + tid * 8);
    }
    __syncthreads();
    f32x4 acc[4][4] = {};
    for (int hc = 0; hc < 16; ++hc) {
        // ---- W1 phase: acc2[half][mf] = A @ W1-chunk (W from global) ----
        f32x4 acc2[2][4];
#pragma unroll
        for (int half = 0; half < 2; ++half) {
            const int h0 = hc * 128 + half * 64;
#pragma unroll
            for (int mf = 0; mf < 4; ++mf) acc2[half][mf] = (f32x4){0.f, 0.f, 0.f, 0.f};
#pragma unroll
            for (int ks = 0; ks < 8; ++ks) {
                short8 wf = *(const short8*)&w1t[(long)(h0 + wn * 16 + fr) * 256 + ks * 32 + q * 8];
#pragma unroll
                for (int mf = 0; mf < 4; ++mf) {
                    int row = mf * 16 + fr;
                    int aby = (row * 512 + ks * 64 + kb2) ^ ((row & 7) << 4);
                    short8 af = *(const short8*)((const char*)As + aby);
                    acc2[half][mf] = __builtin_amdgcn_mfma_f32_16x16x32_bf16(
                        af, wf, acc2[half][mf], 0, 0, 0);
                }
            }
        }
        __syncthreads();   // prior chunk's Hl readers done
        // ---- pack H -> Hl as b32 (col pairs via shfl_xor lane exchange) ----
        {
            const float b1v0 = b1[hc * 128 + wn * 16 + fr];
            const float b1v1 = b1[hc * 128 + 64 + wn * 16 + fr];
#pragma unroll
            for (int mf = 0; mf < 4; ++mf)
#pragma unroll
                for (int i = 0; i < 4; ++i) {
                    int row = mf * 16 + q * 4 + i;
                    unsigned u0 = f2b(fmaxf(acc2[0][mf][i] + b1v0, 0.f));
                    unsigned u1 = f2b(fmaxf(acc2[1][mf][i] + b1v1, 0.f));
                    unsigned p0 = (unsigned)__shfl_xor((int)u0, 1, 64);
                    unsigned p1 = (unsigned)__shfl_xor((int)u1, 1, 64);
                    unsigned word; int col;
                    if ((fr & 1) == 0) { word = u0 | (p0 << 16); col = wn * 16 + fr; }
                    else               { word = p1 | (u1 << 16); col = 64 + wn * 16 + fr - 1; }
                    *(unsigned*)((char*)Hl + row * 288 + col * 2) = word;
                }
        }
        __syncthreads();   // Hl visible to all waves
        // ---- W2 phase: acc += H @ W2-chunk (W from global, H from LDS) ----
#pragma unroll
        for (int kh = 0; kh < 2; ++kh)
#pragma unroll
            for (int ks = 0; ks < 2; ++ks) {
                short8 hf[4];
#pragma unroll
                for (int mf = 0; mf < 4; ++mf) {
                    int row = mf * 16 + fr;
                    hf[mf] = *(const short8*)((const char*)Hl + row * 288 + kh * 128 + ks * 64 + kb2);
                }
#pragma unroll
                for (int nf = 0; nf < 4; ++nf) {
                    short8 wf = *(const short8*)&w2t[(long)(wn * 64 + nf * 16 + fr) * 2048
                                                     + hc * 128 + kh * 64 + ks * 32 + q * 8];
#pragma unroll
                    for (int mf = 0; mf < 4; ++mf)
                        acc[mf][nf] = __builtin_amdgcn_mfma_f32_16x16x32_bf16(
                            hf[mf], wf, acc[mf][nf], 0, 0, 0);
                }
            }
    }
    // epilogue: bf16 out (verified D-mapping)
#pragma unroll
    for (int nf = 0; nf < 4; ++nf) {
        int col = wn * 64 + nf * 16 + fr;
        float bv = b2[col];
#pragma unroll
        for (int mf = 0; mf < 4; ++mf)
#pragma unroll
            for (int i = 0; i < 4; ++i) {
                long r = M0 + mf * 16 + q * 4 + i;
                C[r * (long)ldc + col] = f2b(acc[mf][nf][i] + bv);
            }
    }
}

// =====================================================================
// CSR build: edges grouped by global target row tf = g*NN + tgt
// =====================================================================
__global__ void csr_init(int* __restrict__ cnt, int* __restrict__ fill) {
    int gid = blockIdx.x * blockDim.x + threadIdx.x;
    if (gid < NM) { cnt[gid] = 0; fill[gid] = 0; }
}

__global__ void csr_count(const int* __restrict__ eidx, int* __restrict__ cnt) {
    long el = (long)blockIdx.x * blockDim.x + threadIdx.x;
    if (el >= NE) return;
    int g = (int)(el >> 15), e = (int)(el & (EE - 1));
    int tgt = eidx[((long)g * 2 + 1) * EE + e];
    atomicAdd(&cnt[g * NN + tgt], 1);
}

__global__ __launch_bounds__(1024) void csr_scan(const int* __restrict__ cnt, int* __restrict__ off) {
    __shared__ int part[1024];
    const int t = threadIdx.x;
    const int base = t * (NM / 1024);
    int s = 0;
    for (int i = 0; i < NM / 1024; ++i) s += cnt[base + i];
    part[t] = s;
    __syncthreads();
    for (int d = 1; d < 1024; d <<= 1) {
        int v = (t >= d) ? part[t - d] : 0;
        __syncthreads();
        part[t] += v;
        __syncthreads();
    }
    int run = (t == 0) ? 0 : part[t - 1];
    for (int i = 0; i < NM / 1024; ++i) { off[base + i] = run; run += cnt[base + i]; }
    if (t == 1023) off[NM] = run;
}

__global__ void csr_scatter(const int* __restrict__ eidx, const int* __restrict__ off,
                            int* __restrict__ fill, int* __restrict__ csr) {
    long el = (long)blockIdx.x * blockDim.x + threadIdx.x;
    if (el >= NE) return;
    int g = (int)(el >> 15), e = (int)(el & (EE - 1));
    int tgt = eidx[((long)g * 2 + 1) * EE + e];
    int tf = g * NN + tgt;
    int pos = atomicAdd(&fill[tf], 1);
    csr[off[tf] + pos] = (int)el;
}

// =====================================================================
// Fused TransformerConv on interleaved qkv [NM][768].
// =====================================================================
__global__ __launch_bounds__(256) void conv_fused(
    unsigned short* __restrict__ Z,
    const int* __restrict__ eidx, const float* __restrict__ eattr,
    const float* __restrict__ W_edge, const float* __restrict__ b_edge,
    const int* __restrict__ off, const int* __restrict__ csr)
{
    const int tid = threadIdx.x;
    const int wave = tid >> 6, lane = tid & 63;
    const int bid = (blockIdx.x & 7) * (NM / 4 / 8) + (blockIdx.x >> 3);
    const long tf = (long)bid * 4 + wave;
    const int d0 = lane * 4;
    unsigned short* qrow = &Z[tf * 768];
    const ushort4 q4 = *(const ushort4*)&qrow[d0];
    const float q0 = b2f(q4.x), q1 = b2f(q4.y), q2 = b2f(q4.z), q3 = b2f(q4.w);
    const float be0 = b_edge[d0], be1 = b_edge[d0 + 1],
                be2 = b_edge[d0 + 2], be3 = b_edge[d0 + 3];
    float w0[6], w1r[6], w2r[6], w3r[6];
#pragma unroll
    for (int j2 = 0; j2 < 6; ++j2) {
        const float* wp = &W_edge[j2 * 256 + d0];
        w0[j2] = wp[0]; w1r[j2] = wp[1]; w2r[j2] = wp[2]; w3r[j2] = wp[3];
    }
    float qb = q0 * be0 + q1 * be1 + q2 * be2 + q3 * be3;
    float qw[6];
#pragma unroll
    for (int j2 = 0; j2 < 6; ++j2)
        qw[j2] = q0 * w0[j2] + q1 * w1r[j2] + q2 * w2r[j2] + q3 * w3r[j2];
#pragma unroll
    for (int mm = 1; mm <= 4; mm <<= 1) {
        qb += __shfl_xor(qb, mm, 64);
#pragma unroll
        for (int j2 = 0; j2 < 6; ++j2) qw[j2] += __shfl_xor(qw[j2], mm, 64);
    }
    const float scale = 0.17677669529663687f;  // 1/sqrt(32)
    float s = 0.f, a0 = 0.f, a1 = 0.f, a2 = 0.f, a3 = 0.f;
    float t0 = 0.f, t1 = 0.f, t2 = 0.f, t3 = 0.f, t4 = 0.f, t5 = 0.f;
    const int jb = off[tf], je = off[tf + 1];
    ushort4 kc, vc; float eac[6];
    if (jb < je) {
        const int el = csr[jb];
        const int g = el >> 15, e = el & (EE - 1);
        const int src = eidx[((long)g * 2) * EE + e];
        const long sf = (long)g * NN + src;
        kc = *(const ushort4*)&Z[sf * 768 + 256 + d0];
        vc = *(const ushort4*)&Z[sf * 768 + 512 + d0];
#pragma unroll
        for (int t = 0; t < 6; ++t) eac[t] = eattr[(long)el * 6 + t];
    }
    for (int j = jb; j < je; ++j) {
        ushort4 kn, vn; float ean[6];
        if (j + 1 < je) {
            const int el = csr[j + 1];
            const int g = el >> 15, e = el & (EE - 1);
            const int src = eidx[((long)g * 2) * EE + e];
            const long sf = (long)g * NN + src;
            kn = *(const ushort4*)&Z[sf * 768 + 256 + d0];
            vn = *(const ushort4*)&Z[sf * 768 + 512 + d0];
#pragma unroll
            for (int t = 0; t < 6; ++t) ean[t] = eattr[(long)el * 6 + t];
        }
        float p = q0 * b2f(kc.x) + q1 * b2f(kc.y) + q2 * b2f(kc.z) + q3 * b2f(kc.w);
        p += __shfl_xor(p, 1, 64);
        p += __shfl_xor(p, 2, 64);
        p += __shfl_xor(p, 4, 64);
        float alpha = p + qb;
        alpha += eac[0] * qw[0] + eac[1] * qw[1] + eac[2] * qw[2]
               + eac[3] * qw[3] + eac[4] * qw[4] + eac[5] * qw[5];
        const float a = __expf(alpha * scale);
        s += a;
        a0 += a * b2f(vc.x); a1 += a * b2f(vc.y);
        a2 += a * b2f(vc.z); a3 += a * b2f(vc.w);
        t0 += a * eac[0]; t1 += a * eac[1]; t2 += a * eac[2];
        t3 += a * eac[3]; t4 += a * eac[4]; t5 += a * eac[5];
        kc = kn; vc = vn;
#pragma unroll
        for (int t = 0; t < 6; ++t) eac[t] = ean[t];
    }
    const float inv = (s > 0.f) ? 1.f / s : 0.f;
    float o0 = a0 + be0 * s, o1 = a1 + be1 * s, o2 = a2 + be2 * s, o3 = a3 + be3 * s;
    o0 += w0[0]*t0 + w0[1]*t1 + w0[2]*t2 + w0[3]*t3 + w0[4]*t4 + w0[5]*t5;
    o1 += w1r[0]*t0 + w1r[1]*t1 + w1r[2]*t2 + w1r[3]*t3 + w1r[4]*t4 + w1r[5]*t5;
    o2 += w2r[0]*t0 + w2r[1]*t1 + w2r[2]*t2 + w2r[3]*t3 + w2r[4]*t4 + w2r[5]*t5;
    o3 += w3r[0]*t0 + w3r[1]*t1 + w3r[2]*t2 + w3r[3]*t3 + w3r[4]*t4 + w3r[5]*t5;
    ushort4 o;
    o.x = f2b(o0 * inv); o.y = f2b(o1 * inv);
    o.z = f2b(o2 * inv); o.w = f2b(o3 * inv);
    *(ushort4*)&qrow[d0] = o;
}

// seq(bf16, [t*BN+b*N+n][256]) = conv(q-slice of Z) + skip(k-slice of Z)
__global__ void transpose_add(const unsigned short* __restrict__ Z,
                              unsigned short* __restrict__ out) {
    long gid = (long)blockIdx.x * blockDim.x + threadIdx.x;
    long row = gid >> 6;
    int c4 = (int)(gid & 63);
    int n = (int)(row % NN);
    int bt = (int)(row / NN);
    int t = bt % TT, b = bt / TT;
    long orow = (long)t * BN + (long)b * NN + n;
    ushort4 cv = ((const ushort4*)&Z[row * 768])[c4];
    ushort4 sv = ((const ushort4*)&Z[row * 768 + 256])[c4];
    ushort4 o;
    o.x = f2b(b2f(cv.x) + b2f(sv.x));
    o.y = f2b(b2f(cv.y) + b2f(sv.y));
    o.z = f2b(b2f(cv.z) + b2f(sv.z));
    o.w = f2b(b2f(cv.w) + b2f(sv.w));
    ((ushort4*)out)[orow * 64 + c4] = o;
}

// temporal attention over T=5 on interleaved qkv [NM][768]; o over q-slice.
__global__ __launch_bounds__(256) void mha_time(unsigned short* __restrict__ Z)
{
    const int tid = threadIdx.x;
    const int grp = tid >> 5, c = tid & 31;
    long pair = (long)blockIdx.x * 8 + grp;
    int h = (int)(pair & 7);
    long bn = pair >> 3;
    const float scale = 0.17677669529663687f;
    float qv[TT], kv[TT], vv[TT];
    long r[TT];
#pragma unroll
    for (int t = 0; t < TT; ++t) {
        r[t] = ((long)t * BN + bn) * 768 + h * 32 + c;
        qv[t] = b2f(Z[r[t]]); kv[t] = b2f(Z[r[t] + 256]); vv[t] = b2f(Z[r[t] + 512]);
    }
    float s[TT][TT];
#pragma unroll
    for (int t = 0; t < TT; ++t)
#pragma unroll
        for (int u = 0; u < TT; ++u) {
            float p = qv[t] * kv[u];
#pragma unroll
            for (int m = 16; m >= 1; m >>= 1) p += __shfl_xor(p, m, 64);
            s[t][u] = p * scale;
        }
#pragma unroll
    for (int t = 0; t < TT; ++t) {
        float mx = s[t][0];
#pragma unroll
        for (int u = 1; u < TT; ++u) mx = fmaxf(mx, s[t][u]);
        float sm = 0.f;
#pragma unroll
        for (int u = 0; u < TT; ++u) { s[t][u] = expf(s[t][u] - mx); sm += s[t][u]; }
        float inv = 1.f / sm;
        float o = 0.f;
#pragma unroll
        for (int u = 0; u < TT; ++u) o += s[t][u] * vv[u];
        Z[r[t]] = f2b(o * inv);
    }
}

// seq(bf16) = LayerNorm(seq + res(bf16, row-stride rstride)) * g + b
__global__ __launch_bounds__(256) void ln_residual(
    unsigned short* __restrict__ seq, const unsigned short* __restrict__ res,
    int rstride, const float* __restrict__ g, const float* __restrict__ b)
{
    const int wave = threadIdx.x >> 6, lane = threadIdx.x & 63;
    long row = (long)blockIdx.x * 4 + wave;
    const ushort4 s4 = *(const ushort4*)&seq[row * 256 + lane * 4];
    const ushort4 r4 = *(const ushort4*)&res[row * (long)rstride + lane * 4];
    float x[4] = { b2f(s4.x) + b2f(r4.x), b2f(s4.y) + b2f(r4.y),
                   b2f(s4.z) + b2f(r4.z), b2f(s4.w) + b2f(r4.w) };
    float sum = x[0] + x[1] + x[2] + x[3];
#pragma unroll
    for (int m = 32; m >= 1; m >>= 1) sum += __shfl_xor(sum, m, 64);
    float mean = sum * (1.f / 256.f);
    float vs = 0.f;
#pragma unroll
    for (int i = 0; i < 4; ++i) { float dl = x[i] - mean; vs += dl * dl; }
#pragma unroll
    for (int m = 32; m >= 1; m >>= 1) vs += __shfl_xor(vs, m, 64);
    float inv = rsqrtf(vs * (1.f / 256.f) + 1e-5f);
    ushort4 o;
    o.x = f2b((x[0] - mean) * inv * g[lane * 4 + 0] + b[lane * 4 + 0]);
    o.y = f2b((x[1] - mean) * inv * g[lane * 4 + 1] + b[lane * 4 + 1]);
    o.z = f2b((x[2] - mean) * inv * g[lane * 4 + 2] + b[lane * 4 + 2]);
    o.w = f2b((x[3] - mean) * inv * g[lane * 4 + 3] + b[lane * 4 + 3]);
    *(ushort4*)&seq[row * 256 + lane * 4] = o;
}

// out[row][0..9] = seq[t=T-1 rows](bf16) @ W_out + b_out ; one block per row
__global__ __launch_bounds__(256) void final_out(
    const unsigned short* __restrict__ seq, const float* __restrict__ Wd,
    const float* __restrict__ bd, float* __restrict__ out)
{
    __shared__ float xs[256];
    long row = blockIdx.x;
    xs[threadIdx.x] = b2f(seq[((long)(TT - 1) * BN + row) * 256 + threadIdx.x]);
    __syncthreads();
    const int wv = threadIdx.x >> 6, lane = threadIdx.x & 63;
    for (int o = wv; o < NCLS; o += 4) {
        float p = 0.f;
#pragma unroll
        for (int i = 0; i < 4; ++i) {
            int kk = lane + 64 * i;
            p += xs[kk] * Wd[kk * NCLS + o];
        }
#pragma unroll
        for (int m = 32; m >= 1; m >>= 1) p += __shfl_xor(p, m, 64);
        if (lane == 0) out[row * NCLS + o] = p + bd[o];
    }
}

__global__ void fill_sentinel(float* __restrict__ out, int n) {
    int gid = blockIdx.x * blockDim.x + threadIdx.x;
    if (gid < n) out[gid] = 1.0e6f;
}

// =====================================================================
extern "C" void kernel_launch(void* const* d_in, const int* in_sizes, int n_in,
                              void* d_out, int out_size, void* d_ws, size_t ws_size,
                              hipStream_t stream) {
    const float* xseq  = (const float*)d_in[0];
    const int*   eidx  = (const int*)d_in[1];
    const float* eattr = (const float*)d_in[2];
    const float* W_node = (const float*)d_in[3];
    const float* b_node = (const float*)d_in[4];
    const float* W_edge = (const float*)d_in[5];
    const float* b_edge = (const float*)d_in[6];
    const float* Wq = (const float*)d_in[7];  const float* bq = (const float*)d_in[8];
    const float* Wk = (const float*)d_in[9];  const float* bk = (const float*)d_in[10];
    const float* Wv = (const float*)d_in[11]; const float* bv = (const float*)d_in[12];
    const float* Ws = (const float*)d_in[13]; const float* bs = (const float*)d_in[14];
    const float* Wqkv = (const float*)d_in[15]; const float* bqkv = (const float*)d_in[16];
    const float* Wo = (const float*)d_in[17];   const float* bo = (const float*)d_in[18];
    const float* W1 = (const float*)d_in[19];   const float* b1 = (const float*)d_in[20];
    const float* W2 = (const float*)d_in[21];   const float* b2 = (const float*)d_in[22];
    const float* g_ln1 = (const float*)d_in[23]; const float* b_ln1 = (const float*)d_in[24];
    const float* g_ln2 = (const float*)d_in[25]; const float* b_ln2 = (const float*)d_in[26];
    const float* W_out = (const float*)d_in[27]; const float* b_out = (const float*)d_in[28];
    float* out = (float*)d_out;

    // ---- workspace layout ----
    const long SZ = (long)NM * DD;            // 20,971,520 elements
    unsigned short* Abf = (unsigned short*)d_ws;     // seq activations bf16 (40MB)
    unsigned short* Zu  = Abf + SZ;                  // qkv interleaved [NM][768] (120MB)
    unsigned short* WX = Zu + 3 * SZ;
    unsigned short* xbf = WX;                             // 81920*64
    unsigned short* wtN = xbf + (long)NM * FIN;           // [256][64]
    unsigned short* wtQ = wtN + 256 * 64;                 // [768][256] stacked q,k,v
    unsigned short* wtK = wtQ + 65536;
    unsigned short* wtV = wtK + 65536;
    unsigned short* wtS = wtV + 65536;
    unsigned short* wtQKV = wtS + 65536;                  // 3 * [768][256]
    unsigned short* wtO = wtQKV + 3L * 768 * 256;         // 3 * [256][256]
    unsigned short* wtW1 = wtO + 3L * 65536;              // 3 * [2048][256]
    unsigned short* wtW2 = wtW1 + 3L * 2048 * 256;        // 3 * [256][2048]
    int* cnt  = (int*)(wtW2 + 3L * 256 * 2048);
    int* coff = cnt + NM;                                 // NM+1
    int* cfil = coff + NM + 1;
    int* csr  = cfil + NM;                                // NE ints
    float* qkvb = (float*)(csr + NE);                     // 768 packed bias
    char* wend = (char*)(qkvb + 768);
    const size_t need = (size_t)(wend - (char*)d_ws);
    if (ws_size < need) {
        fill_sentinel<<<dim3((out_size + 255) / 256), dim3(256), 0, stream>>>(out, out_size);
        return;
    }

    dim3 blk(256);
    dim3 tb(32, 8);

    // ---- prologue ----
    xconvert<<<dim3((unsigned)((long)NM * FIN / 4 / 256)), blk, 0, stream>>>(xseq, xbf, (long)NM * FIN / 4);
    wtrans<<<dim3(DD / 32, FIN / 32), tb, 0, stream>>>(W_node, wtN, FIN, DD);
    wtrans<<<dim3(DD / 32, DD / 32), tb, 0, stream>>>(Wq, wtQ, DD, DD);
    wtrans<<<dim3(DD / 32, DD / 32), tb, 0, stream>>>(Wk, wtK, DD, DD);
    wtrans<<<dim3(DD / 32, DD / 32), tb, 0, stream>>>(Wv, wtV, DD, DD);
    wtrans<<<dim3(DD / 32, DD / 32), tb, 0, stream>>>(Ws, wtS, DD, DD);
    pack3<<<dim3(1), blk, 0, stream>>>(bq, bk, bv, qkvb);
    for (int l = 0; l < 3; ++l) {
        wtrans<<<dim3(768 / 32, DD / 32), tb, 0, stream>>>(Wqkv + (long)l * DD * 768, wtQKV + (long)l * 768 * 256, DD, 768);
        wtrans<<<dim3(DD / 32, DD / 32), tb, 0, stream>>>(Wo + (long)l * DD * DD, wtO + (long)l * 65536, DD, DD);
        wtrans<<<dim3(FFD / 32, DD / 32), tb, 0, stream>>>(W1 + (long)l * DD * FFD, wtW1 + (long)l * 2048 * 256, DD, FFD);
        wtrans<<<dim3(DD / 32, FFD / 32), tb, 0, stream>>>(W2 + (long)l * FFD * DD, wtW2 + (long)l * 256 * 2048, FFD, DD);
    }

    // ---- CSR build ----
    csr_init<<<dim3((NM + 255) / 256), blk, 0, stream>>>(cnt, cfil);
    csr_count<<<dim3((unsigned)(NE / 256)), blk, 0, stream>>>(eidx, cnt);
    csr_scan<<<dim3(1), dim3(1024), 0, stream>>>(cnt, coff);
    csr_scatter<<<dim3((unsigned)(NE / 256)), blk, 0, stream>>>(eidx, coff, cfil, csr);

    // ---- stage 1 ----
    gemm_mfma<false, true><<<dim3(NM / 128, DD / 128), blk, 0, stream>>>(
        xbf, FIN, wtN, b_node, Abf, DD, FIN);
    gemm_mfma<false, true><<<dim3(NM / 128, 768 / 128), blk, 0, stream>>>(
        Abf, DD, wtQ, qkvb, Zu, 768, DD);
    conv_fused<<<dim3(NM / 4), blk, 0, stream>>>(
        Zu, eidx, eattr, W_edge, b_edge, coff, csr);
    gemm_mfma<false, true><<<dim3(NM / 128, DD / 128), blk, 0, stream>>>(
        Abf, DD, wtS, bs, (void*)(Zu + 256), 768, DD);
    transpose_add<<<dim3(NM * 64 / 256), blk, 0, stream>>>(Zu, Abf);

    // ---- stage 2: 3 temporal transformer encoder layers ----
    for (int l = 0; l < 3; ++l) {
        gemm_mfma<false, true><<<dim3(NM / 128, 768 / 128), blk, 0, stream>>>(
            Abf, DD, wtQKV + (long)l * 768 * 256, bqkv + (long)l * 768, Zu, 768, DD);
        mha_time<<<dim3(BN * HH / 8), blk, 0, stream>>>(Zu);
        gemm_mfma<false, true><<<dim3(NM / 128, DD / 128), blk, 0, stream>>>(
            Zu, 768, wtO + (long)l * 65536, bo + (long)l * DD, (void*)(Zu + 512), 768, DD);
        ln_residual<<<dim3(NM / 4), blk, 0, stream>>>(
            Abf, Zu + 512, 768, g_ln1 + l * DD, b_ln1 + l * DD);
        // fused FFN v2: Hid on-chip; result -> Zu q-slice (stride 768)
        ffn_fused<<<dim3(NM / 64), blk, 0, stream>>>(
            Abf, wtW1 + (long)l * 2048 * 256, wtW2 + (long)l * 256 * 2048,
            b1 + (long)l * FFD, b2 + (long)l * DD, Zu, 768);
        ln_residual<<<dim3(NM / 4), blk, 0, stream>>>(
            Abf, Zu, 768, g_ln2 + l * DD, b_ln2 + l * DD);
    }

    // ---- output head ----
    final_out<<<dim3(BN), blk, 0, stream>>>(Abf, W_out, b_out, out);
}

// Round 10
// 2420.882 us; speedup vs baseline: 1.1765x; 1.1765x over previous
//
#include <hip/hip_runtime.h>
#include <math.h>

// ---- problem constants ----
#define BB   8
#define TT   5
#define NN   2048
#define FIN  64
#define EE   32768
#define DD   256
#define HH   8
#define FFD  2048
#define NCLS 10
#define GG   (BB*TT)        // 40 graphs
#define BN   (BB*NN)        // 16384
#define NM   (GG*NN)        // 81920 rows (= TT*BN)
#define NE   ((long)GG*EE)  // 1310720 edges

#define MR        16384           // rows per FFN chunk (5 chunks)

typedef __attribute__((ext_vector_type(8))) short short8;
typedef __attribute__((ext_vector_type(4))) float f32x4;

// ---- bf16 helpers (RNE) ----
__device__ __forceinline__ unsigned short f2b(float f) {
    unsigned u = __float_as_uint(f);
    u = (u + 0x7fffu + ((u >> 16) & 1u)) >> 16;
    return (unsigned short)u;
}
__device__ __forceinline__ float b2f(unsigned short b) {
    return __uint_as_float(((unsigned)b) << 16);
}

// async global->LDS, 16B per lane (dest must be wave-uniform base + lane*16)
__device__ __forceinline__ void gload_lds16(const void* g, void* l) {
    __builtin_amdgcn_global_load_lds(
        (__attribute__((address_space(1))) void*)g,
        (__attribute__((address_space(3))) void*)l, 16, 0, 0);
}

// =====================================================================
// Weight transpose+convert: in fp32 [K][N] row-major -> out bf16 [N][K]
// =====================================================================
__global__ void wtrans(const float* __restrict__ in, unsigned short* __restrict__ out,
                       int K, int N) {
    __shared__ float t[32][33];
    const int n0 = blockIdx.x * 32, k0 = blockIdx.y * 32;
    const int tx = threadIdx.x, ty = threadIdx.y;
    for (int i = ty; i < 32; i += 8) t[i][tx] = in[(long)(k0 + i) * N + n0 + tx];
    __syncthreads();
    for (int i = ty; i < 32; i += 8)
        out[(long)(n0 + i) * K + k0 + tx] = f2b(t[tx][i]);
}

// fp32 -> bf16 elementwise (n4 float4 groups)
__global__ void xconvert(const float* __restrict__ in, unsigned short* __restrict__ out, long n4) {
    long gid = (long)blockIdx.x * blockDim.x + threadIdx.x;
    if (gid >= n4) return;
    float4 v = ((const float4*)in)[gid];
    ushort4 o;
    o.x = f2b(v.x); o.y = f2b(v.y); o.z = f2b(v.z); o.w = f2b(v.w);
    ((ushort4*)out)[gid] = o;
}

// pack 3 bias vectors of 256 into one 768 buffer
__global__ void pack3(const float* __restrict__ a, const float* __restrict__ b,
                      const float* __restrict__ c, float* __restrict__ o) {
    int i = threadIdx.x;
    o[i] = a[i]; o[256 + i] = b[i]; o[512 + i] = c[i];
}

// =====================================================================
// bf16 MFMA GEMM, BK=64 + XOR-swizzled LDS (rule-21 compliant: linear
// gload_lds dest + source-chunk swizzle + same XOR on b128 reads).
// C[M x N] = A[M x K] @ W[K x N] + bias. K % 64 == 0.
// 128x128 tile, 256 threads = 4 waves (2x2), 16x16x32 MFMA, XCD swizzle.
// =====================================================================
template <bool RELU, bool OUTBF>
__global__ __launch_bounds__(256) void gemm_mfma(
    const unsigned short* __restrict__ A, int lda,
    const unsigned short* __restrict__ WT,
    const float* __restrict__ bias,
    void* __restrict__ Cv, int ldc, int K)
{
    __shared__ unsigned short As[128 * 64];
    __shared__ unsigned short Bs[128 * 64];
    const int tid = threadIdx.x;
    const int wid = tid >> 6, lane = tid & 63;
    const int wm = wid >> 1, wn = wid & 1;
    const int gx = gridDim.x, gy = gridDim.y;
    int bx = blockIdx.x, by = blockIdx.y;
    if ((gx & 7) == 0) {
        const int lbid = bx + gx * by;
        const int xcd = lbid & 7;
        const int i = lbid >> 3;
        const int CX = gx >> 3;
        bx = xcd * CX + i / gy;
        by = i - (i / gy) * gy;
    }
    const long row0 = (long)bx * 128;
    const long col0 = (long)by * 128;
    const int srow = tid >> 3;            // 0..31 (per pass)
    const int schunk = tid & 7;           // 16B chunk in 128B row
    const int fr = lane & 15;
    const int q = lane >> 4;
    f32x4 acc[4][4] = {};
    for (int k0 = 0; k0 < K; k0 += 64) {
        __syncthreads();
#pragma unroll
        for (int p = 0; p < 4; ++p) {
            const int row = p * 32 + srow;
            const int sc = (schunk ^ (row & 7)) * 8;
            gload_lds16(&A[(row0 + row) * (long)lda + k0 + sc], As + row * 64 + schunk * 8);
            gload_lds16(&WT[(col0 + row) * (long)K + k0 + sc], Bs + row * 64 + schunk * 8);
        }
        __syncthreads();
#pragma unroll
        for (int kk = 0; kk < 2; ++kk) {
            short8 af[4], bfr[4];
#pragma unroll
            for (int mf = 0; mf < 4; ++mf) {
                const int row = wm * 64 + mf * 16 + fr;
                const int byo = (row * 128 + kk * 64 + q * 16) ^ ((row & 7) << 4);
                af[mf] = *(const short8*)((const char*)As + byo);
            }
#pragma unroll
            for (int nf = 0; nf < 4; ++nf) {
                const int row = wn * 64 + nf * 16 + fr;
                const int byo = (row * 128 + kk * 64 + q * 16) ^ ((row & 7) << 4);
                bfr[nf] = *(const short8*)((const char*)Bs + byo);
            }
#pragma unroll
            for (int mf = 0; mf < 4; ++mf)
#pragma unroll
                for (int nf = 0; nf < 4; ++nf)
                    acc[mf][nf] = __builtin_amdgcn_mfma_f32_16x16x32_bf16(
                        af[mf], bfr[nf], acc[mf][nf], 0, 0, 0);
        }
    }
#pragma unroll
    for (int nf = 0; nf < 4; ++nf) {
        const long col = col0 + wn * 64 + nf * 16 + fr;
        const float bv = bias[col];
#pragma unroll
        for (int mf = 0; mf < 4; ++mf) {
#pragma unroll
            for (int i = 0; i < 4; ++i) {
                const long r = row0 + wm * 64 + mf * 16 + q * 4 + i;
                float vv = acc[mf][nf][i] + bv;
                if (RELU) vv = fmaxf(vv, 0.f);
                if (OUTBF) ((unsigned short*)Cv)[r * ldc + col] = f2b(vv);
                else       ((float*)Cv)[r * ldc + col] = vv;
            }
        }
    }
}

// =====================================================================
// CSR build: edges grouped by global target row tf = g*NN + tgt
// =====================================================================
__global__ void csr_init(int* __restrict__ cnt, int* __restrict__ fill) {
    int gid = blockIdx.x * blockDim.x + threadIdx.x;
    if (gid < NM) { cnt[gid] = 0; fill[gid] = 0; }
}

__global__ void csr_count(const int* __restrict__ eidx, int* __restrict__ cnt) {
    long el = (long)blockIdx.x * blockDim.x + threadIdx.x;
    if (el >= NE) return;
    int g = (int)(el >> 15), e = (int)(el & (EE - 1));
    int tgt = eidx[((long)g * 2 + 1) * EE + e];
    atomicAdd(&cnt[g * NN + tgt], 1);
}

__global__ __launch_bounds__(1024) void csr_scan(const int* __restrict__ cnt, int* __restrict__ off) {
    __shared__ int part[1024];
    const int t = threadIdx.x;
    const int base = t * (NM / 1024);
    int s = 0;
    for (int i = 0; i < NM / 1024; ++i) s += cnt[base + i];
    part[t] = s;
    __syncthreads();
    for (int d = 1; d < 1024; d <<= 1) {
        int v = (t >= d) ? part[t - d] : 0;
        __syncthreads();
        part[t] += v;
        __syncthreads();
    }
    int run = (t == 0) ? 0 : part[t - 1];
    for (int i = 0; i < NM / 1024; ++i) { off[base + i] = run; run += cnt[base + i]; }
    if (t == 1023) off[NM] = run;
}

__global__ void csr_scatter(const int* __restrict__ eidx, const int* __restrict__ off,
                            int* __restrict__ fill, int* __restrict__ csr) {
    long el = (long)blockIdx.x * blockDim.x + threadIdx.x;
    if (el >= NE) return;
    int g = (int)(el >> 15), e = (int)(el & (EE - 1));
    int tgt = eidx[((long)g * 2 + 1) * EE + e];
    int tf = g * NN + tgt;
    int pos = atomicAdd(&fill[tf], 1);
    csr[off[tf] + pos] = (int)el;
}

// =====================================================================
// Fused TransformerConv on interleaved qkv [NM][768].
// =====================================================================
__global__ __launch_bounds__(256) void conv_fused(
    unsigned short* __restrict__ Z,
    const int* __restrict__ eidx, const float* __restrict__ eattr,
    const float* __restrict__ W_edge, const float* __restrict__ b_edge,
    const int* __restrict__ off, const int* __restrict__ csr)
{
    const int tid = threadIdx.x;
    const int wave = tid >> 6, lane = tid & 63;
    const int bid = (blockIdx.x & 7) * (NM / 4 / 8) + (blockIdx.x >> 3);
    const long tf = (long)bid * 4 + wave;
    const int d0 = lane * 4;
    unsigned short* qrow = &Z[tf * 768];
    const ushort4 q4 = *(const ushort4*)&qrow[d0];
    const float q0 = b2f(q4.x), q1 = b2f(q4.y), q2 = b2f(q4.z), q3 = b2f(q4.w);
    const float be0 = b_edge[d0], be1 = b_edge[d0 + 1],
                be2 = b_edge[d0 + 2], be3 = b_edge[d0 + 3];
    float w0[6], w1r[6], w2r[6], w3r[6];
#pragma unroll
    for (int j2 = 0; j2 < 6; ++j2) {
        const float* wp = &W_edge[j2 * 256 + d0];
        w0[j2] = wp[0]; w1r[j2] = wp[1]; w2r[j2] = wp[2]; w3r[j2] = wp[3];
    }
    float qb = q0 * be0 + q1 * be1 + q2 * be2 + q3 * be3;
    float qw[6];
#pragma unroll
    for (int j2 = 0; j2 < 6; ++j2)
        qw[j2] = q0 * w0[j2] + q1 * w1r[j2] + q2 * w2r[j2] + q3 * w3r[j2];
#pragma unroll
    for (int mm = 1; mm <= 4; mm <<= 1) {
        qb += __shfl_xor(qb, mm, 64);
#pragma unroll
        for (int j2 = 0; j2 < 6; ++j2) qw[j2] += __shfl_xor(qw[j2], mm, 64);
    }
    const float scale = 0.17677669529663687f;  // 1/sqrt(32)
    float s = 0.f, a0 = 0.f, a1 = 0.f, a2 = 0.f, a3 = 0.f;
    float t0 = 0.f, t1 = 0.f, t2 = 0.f, t3 = 0.f, t4 = 0.f, t5 = 0.f;
    const int jb = off[tf], je = off[tf + 1];
    ushort4 kc, vc; float eac[6];
    if (jb < je) {
        const int el = csr[jb];
        const int g = el >> 15, e = el & (EE - 1);
        const int src = eidx[((long)g * 2) * EE + e];
        const long sf = (long)g * NN + src;
        kc = *(const ushort4*)&Z[sf * 768 + 256 + d0];
        vc = *(const ushort4*)&Z[sf * 768 + 512 + d0];
#pragma unroll
        for (int t = 0; t < 6; ++t) eac[t] = eattr[(long)el * 6 + t];
    }
    for (int j = jb; j < je; ++j) {
        ushort4 kn, vn; float ean[6];
        if (j + 1 < je) {
            const int el = csr[j + 1];
            const int g = el >> 15, e = el & (EE - 1);
            const int src = eidx[((long)g * 2) * EE + e];
            const long sf = (long)g * NN + src;
            kn = *(const ushort4*)&Z[sf * 768 + 256 + d0];
            vn = *(const ushort4*)&Z[sf * 768 + 512 + d0];
#pragma unroll
            for (int t = 0; t < 6; ++t) ean[t] = eattr[(long)el * 6 + t];
        }
        float p = q0 * b2f(kc.x) + q1 * b2f(kc.y) + q2 * b2f(kc.z) + q3 * b2f(kc.w);
        p += __shfl_xor(p, 1, 64);
        p += __shfl_xor(p, 2, 64);
        p += __shfl_xor(p, 4, 64);
        float alpha = p + qb;
        alpha += eac[0] * qw[0] + eac[1] * qw[1] + eac[2] * qw[2]
               + eac[3] * qw[3] + eac[4] * qw[4] + eac[5] * qw[5];
        const float a = __expf(alpha * scale);
        s += a;
        a0 += a * b2f(vc.x); a1 += a * b2f(vc.y);
        a2 += a * b2f(vc.z); a3 += a * b2f(vc.w);
        t0 += a * eac[0]; t1 += a * eac[1]; t2 += a * eac[2];
        t3 += a * eac[3]; t4 += a * eac[4]; t5 += a * eac[5];
        kc = kn; vc = vn;
#pragma unroll
        for (int t = 0; t < 6; ++t) eac[t] = ean[t];
    }
    const float inv = (s > 0.f) ? 1.f / s : 0.f;
    float o0 = a0 + be0 * s, o1 = a1 + be1 * s, o2 = a2 + be2 * s, o3 = a3 + be3 * s;
    o0 += w0[0]*t0 + w0[1]*t1 + w0[2]*t2 + w0[3]*t3 + w0[4]*t4 + w0[5]*t5;
    o1 += w1r[0]*t0 + w1r[1]*t1 + w1r[2]*t2 + w1r[3]*t3 + w1r[4]*t4 + w1r[5]*t5;
    o2 += w2r[0]*t0 + w2r[1]*t1 + w2r[2]*t2 + w2r[3]*t3 + w2r[4]*t4 + w2r[5]*t5;
    o3 += w3r[0]*t0 + w3r[1]*t1 + w3r[2]*t2 + w3r[3]*t3 + w3r[4]*t4 + w3r[5]*t5;
    ushort4 o;
    o.x = f2b(o0 * inv); o.y = f2b(o1 * inv);
    o.z = f2b(o2 * inv); o.w = f2b(o3 * inv);
    *(ushort4*)&qrow[d0] = o;
}

// seq(bf16, [t*BN+b*N+n][256]) = conv(q-slice of Z) + skip(k-slice of Z)
__global__ void transpose_add(const unsigned short* __restrict__ Z,
                              unsigned short* __restrict__ out) {
    long gid = (long)blockIdx.x * blockDim.x + threadIdx.x;
    long row = gid >> 6;
    int c4 = (int)(gid & 63);
    int n = (int)(row % NN);
    int bt = (int)(row / NN);
    int t = bt % TT, b = bt / TT;
    long orow = (long)t * BN + (long)b * NN + n;
    ushort4 cv = ((const ushort4*)&Z[row * 768])[c4];
    ushort4 sv = ((const ushort4*)&Z[row * 768 + 256])[c4];
    ushort4 o;
    o.x = f2b(b2f(cv.x) + b2f(sv.x));
    o.y = f2b(b2f(cv.y) + b2f(sv.y));
    o.z = f2b(b2f(cv.z) + b2f(sv.z));
    o.w = f2b(b2f(cv.w) + b2f(sv.w));
    ((ushort4*)out)[orow * 64 + c4] = o;
}

// temporal attention over T=5 on interleaved qkv [NM][768]; o over q-slice.
__global__ __launch_bounds__(256) void mha_time(unsigned short* __restrict__ Z)
{
    const int tid = threadIdx.x;
    const int grp = tid >> 5, c = tid & 31;
    long pair = (long)blockIdx.x * 8 + grp;
    int h = (int)(pair & 7);
    long bn = pair >> 3;
    const float scale = 0.17677669529663687f;
    float qv[TT], kv[TT], vv[TT];
    long r[TT];
#pragma unroll
    for (int t = 0; t < TT; ++t) {
        r[t] = ((long)t * BN + bn) * 768 + h * 32 + c;
        qv[t] = b2f(Z[r[t]]); kv[t] = b2f(Z[r[t] + 256]); vv[t] = b2f(Z[r[t] + 512]);
    }
    float s[TT][TT];
#pragma unroll
    for (int t = 0; t < TT; ++t)
#pragma unroll
        for (int u = 0; u < TT; ++u) {
            float p = qv[t] * kv[u];
#pragma unroll
            for (int m = 16; m >= 1; m >>= 1) p += __shfl_xor(p, m, 64);
            s[t][u] = p * scale;
        }
#pragma unroll
    for (int t = 0; t < TT; ++t) {
        float mx = s[t][0];
#pragma unroll
        for (int u = 1; u < TT; ++u) mx = fmaxf(mx, s[t][u]);
        float sm = 0.f;
#pragma unroll
        for (int u = 0; u < TT; ++u) { s[t][u] = expf(s[t][u] - mx); sm += s[t][u]; }
        float inv = 1.f / sm;
        float o = 0.f;
#pragma unroll
        for (int u = 0; u < TT; ++u) o += s[t][u] * vv[u];
        Z[r[t]] = f2b(o * inv);
    }
}

// seq(bf16) = LayerNorm(seq + res(bf16, row-stride rstride)) * g + b
__global__ __launch_bounds__(256) void ln_residual(
    unsigned short* __restrict__ seq, const unsigned short* __restrict__ res,
    int rstride, const float* __restrict__ g, const float* __restrict__ b)
{
    const int wave = threadIdx.x >> 6, lane = threadIdx.x & 63;
    long row = (long)blockIdx.x * 4 + wave;
    const ushort4 s4 = *(const ushort4*)&seq[row * 256 + lane * 4];
    const ushort4 r4 = *(const ushort4*)&res[row * (long)rstride + lane * 4];
    float x[4] = { b2f(s4.x) + b2f(r4.x), b2f(s4.y) + b2f(r4.y),
                   b2f(s4.z) + b2f(r4.z), b2f(s4.w) + b2f(r4.w) };
    float sum = x[0] + x[1] + x[2] + x[3];
#pragma unroll
    for (int m = 32; m >= 1; m >>= 1) sum += __shfl_xor(sum, m, 64);
    float mean = sum * (1.f / 256.f);
    float vs = 0.f;
#pragma unroll
    for (int i = 0; i < 4; ++i) { float dl = x[i] - mean; vs += dl * dl; }
#pragma unroll
    for (int m = 32; m >= 1; m >>= 1) vs += __shfl_xor(vs, m, 64);
    float inv = rsqrtf(vs * (1.f / 256.f) + 1e-5f);
    ushort4 o;
    o.x = f2b((x[0] - mean) * inv * g[lane * 4 + 0] + b[lane * 4 + 0]);
    o.y = f2b((x[1] - mean) * inv * g[lane * 4 + 1] + b[lane * 4 + 1]);
    o.z = f2b((x[2] - mean) * inv * g[lane * 4 + 2] + b[lane * 4 + 2]);
    o.w = f2b((x[3] - mean) * inv * g[lane * 4 + 3] + b[lane * 4 + 3]);
    *(ushort4*)&seq[row * 256 + lane * 4] = o;
}

// out[row][0..9] = seq[t=T-1 rows](bf16) @ W_out + b_out ; one block per row
__global__ __launch_bounds__(256) void final_out(
    const unsigned short* __restrict__ seq, const float* __restrict__ Wd,
    const float* __restrict__ bd, float* __restrict__ out)
{
    __shared__ float xs[256];
    long row = blockIdx.x;
    xs[threadIdx.x] = b2f(seq[((long)(TT - 1) * BN + row) * 256 + threadIdx.x]);
    __syncthreads();
    const int wv = threadIdx.x >> 6, lane = threadIdx.x & 63;
    for (int o = wv; o < NCLS; o += 4) {
        float p = 0.f;
#pragma unroll
        for (int i = 0; i < 4; ++i) {
            int kk = lane + 64 * i;
            p += xs[kk] * Wd[kk * NCLS + o];
        }
#pragma unroll
        for (int m = 32; m >= 1; m >>= 1) p += __shfl_xor(p, m, 64);
        if (lane == 0) out[row * NCLS + o] = p + bd[o];
    }
}

__global__ void fill_sentinel(float* __restrict__ out, int n) {
    int gid = blockIdx.x * blockDim.x + threadIdx.x;
    if (gid < n) out[gid] = 1.0e6f;
}

// =====================================================================
extern "C" void kernel_launch(void* const* d_in, const int* in_sizes, int n_in,
                              void* d_out, int out_size, void* d_ws, size_t ws_size,
                              hipStream_t stream) {
    const float* xseq  = (const float*)d_in[0];
    const int*   eidx  = (const int*)d_in[1];
    const float* eattr = (const float*)d_in[2];
    const float* W_node = (const float*)d_in[3];
    const float* b_node = (const float*)d_in[4];
    const float* W_edge = (const float*)d_in[5];
    const float* b_edge = (const float*)d_in[6];
    const float* Wq = (const float*)d_in[7];  const float* bq = (const float*)d_in[8];
    const float* Wk = (const float*)d_in[9];  const float* bk = (const float*)d_in[10];
    const float* Wv = (const float*)d_in[11]; const float* bv = (const float*)d_in[12];
    const float* Ws = (const float*)d_in[13]; const float* bs = (const float*)d_in[14];
    const float* Wqkv = (const float*)d_in[15]; const float* bqkv = (const float*)d_in[16];
    const float* Wo = (const float*)d_in[17];   const float* bo = (const float*)d_in[18];
    const float* W1 = (const float*)d_in[19];   const float* b1 = (const float*)d_in[20];
    const float* W2 = (const float*)d_in[21];   const float* b2 = (const float*)d_in[22];
    const float* g_ln1 = (const float*)d_in[23]; const float* b_ln1 = (const float*)d_in[24];
    const float* g_ln2 = (const float*)d_in[25]; const float* b_ln2 = (const float*)d_in[26];
    const float* W_out = (const float*)d_in[27]; const float* b_out = (const float*)d_in[28];
    float* out = (float*)d_out;

    // ---- workspace layout ----
    const long SZ = (long)NM * DD;            // 20,971,520 elements
    unsigned short* Abf = (unsigned short*)d_ws;     // seq activations bf16 (40MB)
    unsigned short* Zu  = Abf + SZ;                  // qkv interleaved [NM][768] (120MB)
    unsigned short* Hid = Zu;                        // FFN hidden bf16 [MR][2048] (64MB)
    unsigned short* res2B = Zu + (long)MR * FFD;     // FFN residual bf16 [MR][256] (8MB)
    unsigned short* WX = Zu + 3 * SZ;
    unsigned short* xbf = WX;                             // 81920*64
    unsigned short* wtN = xbf + (long)NM * FIN;           // [256][64]
    unsigned short* wtQ = wtN + 256 * 64;                 // [768][256] stacked q,k,v
    unsigned short* wtK = wtQ + 65536;
    unsigned short* wtV = wtK + 65536;
    unsigned short* wtS = wtV + 65536;
    unsigned short* wtQKV = wtS + 65536;                  // 3 * [768][256]
    unsigned short* wtO = wtQKV + 3L * 768 * 256;         // 3 * [256][256]
    unsigned short* wtW1 = wtO + 3L * 65536;              // 3 * [2048][256]
    unsigned short* wtW2 = wtW1 + 3L * 2048 * 256;        // 3 * [256][2048]
    int* cnt  = (int*)(wtW2 + 3L * 256 * 2048);
    int* coff = cnt + NM;                                 // NM+1
    int* cfil = coff + NM + 1;
    int* csr  = cfil + NM;                                // NE ints
    float* qkvb = (float*)(csr + NE);                     // 768 packed bias
    char* wend = (char*)(qkvb + 768);
    const size_t need = (size_t)(wend - (char*)d_ws);
    if (ws_size < need) {
        fill_sentinel<<<dim3((out_size + 255) / 256), dim3(256), 0, stream>>>(out, out_size);
        return;
    }

    dim3 blk(256);
    dim3 tb(32, 8);

    // ---- prologue ----
    xconvert<<<dim3((unsigned)((long)NM * FIN / 4 / 256)), blk, 0, stream>>>(xseq, xbf, (long)NM * FIN / 4);
    wtrans<<<dim3(DD / 32, FIN / 32), tb, 0, stream>>>(W_node, wtN, FIN, DD);
    wtrans<<<dim3(DD / 32, DD / 32), tb, 0, stream>>>(Wq, wtQ, DD, DD);
    wtrans<<<dim3(DD / 32, DD / 32), tb, 0, stream>>>(Wk, wtK, DD, DD);
    wtrans<<<dim3(DD / 32, DD / 32), tb, 0, stream>>>(Wv, wtV, DD, DD);
    wtrans<<<dim3(DD / 32, DD / 32), tb, 0, stream>>>(Ws, wtS, DD, DD);
    pack3<<<dim3(1), blk, 0, stream>>>(bq, bk, bv, qkvb);
    for (int l = 0; l < 3; ++l) {
        wtrans<<<dim3(768 / 32, DD / 32), tb, 0, stream>>>(Wqkv + (long)l * DD * 768, wtQKV + (long)l * 768 * 256, DD, 768);
        wtrans<<<dim3(DD / 32, DD / 32), tb, 0, stream>>>(Wo + (long)l * DD * DD, wtO + (long)l * 65536, DD, DD);
        wtrans<<<dim3(FFD / 32, DD / 32), tb, 0, stream>>>(W1 + (long)l * DD * FFD, wtW1 + (long)l * 2048 * 256, DD, FFD);
        wtrans<<<dim3(DD / 32, FFD / 32), tb, 0, stream>>>(W2 + (long)l * FFD * DD, wtW2 + (long)l * 256 * 2048, FFD, DD);
    }

    // ---- CSR build ----
    csr_init<<<dim3((NM + 255) / 256), blk, 0, stream>>>(cnt, cfil);
    csr_count<<<dim3((unsigned)(NE / 256)), blk, 0, stream>>>(eidx, cnt);
    csr_scan<<<dim3(1), dim3(1024), 0, stream>>>(cnt, coff);
    csr_scatter<<<dim3((unsigned)(NE / 256)), blk, 0, stream>>>(eidx, coff, cfil, csr);

    // ---- stage 1 ----
    gemm_mfma<false, true><<<dim3(NM / 128, DD / 128), blk, 0, stream>>>(
        xbf, FIN, wtN, b_node, Abf, DD, FIN);
    gemm_mfma<false, true><<<dim3(NM / 128, 768 / 128), blk, 0, stream>>>(
        Abf, DD, wtQ, qkvb, Zu, 768, DD);
    conv_fused<<<dim3(NM / 4), blk, 0, stream>>>(
        Zu, eidx, eattr, W_edge, b_edge, coff, csr);
    gemm_mfma<false, true><<<dim3(NM / 128, DD / 128), blk, 0, stream>>>(
        Abf, DD, wtS, bs, (void*)(Zu + 256), 768, DD);
    transpose_add<<<dim3(NM * 64 / 256), blk, 0, stream>>>(Zu, Abf);

    // ---- stage 2: 3 temporal transformer encoder layers ----
    for (int l = 0; l < 3; ++l) {
        gemm_mfma<false, true><<<dim3(NM / 128, 768 / 128), blk, 0, stream>>>(
            Abf, DD, wtQKV + (long)l * 768 * 256, bqkv + (long)l * 768, Zu, 768, DD);
        mha_time<<<dim3(BN * HH / 8), blk, 0, stream>>>(Zu);
        gemm_mfma<false, true><<<dim3(NM / 128, DD / 128), blk, 0, stream>>>(
            Zu, 768, wtO + (long)l * 65536, bo + (long)l * DD, (void*)(Zu + 512), 768, DD);
        ln_residual<<<dim3(NM / 4), blk, 0, stream>>>(
            Abf, Zu + 512, 768, g_ln1 + l * DD, b_ln1 + l * DD);
        // unfused FFN (register-pressure-safe), hidden in Zu region
        for (int mr = 0; mr < NM / MR; ++mr) {
            const long r0 = (long)mr * MR;
            gemm_mfma<true, true><<<dim3(MR / 128, FFD / 128), blk, 0, stream>>>(
                Abf + r0 * DD, DD, wtW1 + (long)l * 2048 * 256, b1 + (long)l * FFD, Hid, FFD, DD);
            gemm_mfma<false, true><<<dim3(MR / 128, DD / 128), blk, 0, stream>>>(
                Hid, FFD, wtW2 + (long)l * 256 * 2048, b2 + (long)l * DD, res2B, DD, FFD);
            ln_residual<<<dim3(MR / 4), blk, 0, stream>>>(
                Abf + r0 * DD, res2B, DD, g_ln2 + l * DD, b_ln2 + l * DD);
        }
    }

    // ---- output head ----
    final_out<<<dim3(BN), blk, 0, stream>>>(Abf, W_out, b_out, out);
}

// Round 11
// 2402.842 us; speedup vs baseline: 1.1853x; 1.0075x over previous
//
#include <hip/hip_runtime.h>
#include <math.h>

// ---- problem constants ----
#define BB   8
#define TT   5
#define NN   2048
#define FIN  64
#define EE   32768
#define DD   256
#define HH   8
#define FFD  2048
#define NCLS 10
#define GG   (BB*TT)        // 40 graphs
#define BN   (BB*NN)        // 16384
#define NM   (GG*NN)        // 81920 rows (= TT*BN)
#define NE   ((long)GG*EE)  // 1310720 edges

#define MR        16384           // rows per FFN chunk (5 chunks)

typedef __attribute__((ext_vector_type(8))) short short8;
typedef __attribute__((ext_vector_type(4))) float f32x4;

// ---- bf16 helpers (RNE) ----
__device__ __forceinline__ unsigned short f2b(float f) {
    unsigned u = __float_as_uint(f);
    u = (u + 0x7fffu + ((u >> 16) & 1u)) >> 16;
    return (unsigned short)u;
}
__device__ __forceinline__ float b2f(unsigned short b) {
    return __uint_as_float(((unsigned)b) << 16);
}

// async global->LDS, 16B per lane (dest must be wave-uniform base + lane*16)
__device__ __forceinline__ void gload_lds16(const void* g, void* l) {
    __builtin_amdgcn_global_load_lds(
        (__attribute__((address_space(1))) void*)g,
        (__attribute__((address_space(3))) void*)l, 16, 0, 0);
}

// =====================================================================
// Weight transpose+convert: in fp32 [K][N] row-major -> out bf16 [N][K]
// =====================================================================
__global__ void wtrans(const float* __restrict__ in, unsigned short* __restrict__ out,
                       int K, int N) {
    __shared__ float t[32][33];
    const int n0 = blockIdx.x * 32, k0 = blockIdx.y * 32;
    const int tx = threadIdx.x, ty = threadIdx.y;
    for (int i = ty; i < 32; i += 8) t[i][tx] = in[(long)(k0 + i) * N + n0 + tx];
    __syncthreads();
    for (int i = ty; i < 32; i += 8)
        out[(long)(n0 + i) * K + k0 + tx] = f2b(t[tx][i]);
}

// fp32 -> bf16 elementwise (n4 float4 groups)
__global__ void xconvert(const float* __restrict__ in, unsigned short* __restrict__ out, long n4) {
    long gid = (long)blockIdx.x * blockDim.x + threadIdx.x;
    if (gid >= n4) return;
    float4 v = ((const float4*)in)[gid];
    ushort4 o;
    o.x = f2b(v.x); o.y = f2b(v.y); o.z = f2b(v.z); o.w = f2b(v.w);
    ((ushort4*)out)[gid] = o;
}

// pack 3 bias vectors of 256 into one 768 buffer
__global__ void pack3(const float* __restrict__ a, const float* __restrict__ b,
                      const float* __restrict__ c, float* __restrict__ o) {
    int i = threadIdx.x;
    o[i] = a[i]; o[256 + i] = b[i]; o[512 + i] = c[i];
}

// =====================================================================
// bf16 MFMA GEMM, BK=64 + XOR-swizzled LDS (rule-21 compliant: linear
// gload_lds dest + source-chunk swizzle + same XOR on b128 reads).
// C[M x N] = A[M x K] @ W[K x N] + bias. K % 64 == 0.
// 128x128 tile, 256 threads = 4 waves (2x2), 16x16x32 MFMA, XCD swizzle.
// =====================================================================
template <bool RELU, bool OUTBF>
__global__ __launch_bounds__(256) void gemm_mfma(
    const unsigned short* __restrict__ A, int lda,
    const unsigned short* __restrict__ WT,
    const float* __restrict__ bias,
    void* __restrict__ Cv, int ldc, int K)
{
    __shared__ unsigned short As[128 * 64];
    __shared__ unsigned short Bs[128 * 64];
    const int tid = threadIdx.x;
    const int wid = tid >> 6, lane = tid & 63;
    const int wm = wid >> 1, wn = wid & 1;
    const int gx = gridDim.x, gy = gridDim.y;
    int bx = blockIdx.x, by = blockIdx.y;
    if ((gx & 7) == 0) {
        const int lbid = bx + gx * by;
        const int xcd = lbid & 7;
        const int i = lbid >> 3;
        const int CX = gx >> 3;
        bx = xcd * CX + i / gy;
        by = i - (i / gy) * gy;
    }
    const long row0 = (long)bx * 128;
    const long col0 = (long)by * 128;
    const int srow = tid >> 3;            // 0..31 (per pass)
    const int schunk = tid & 7;           // 16B chunk in 128B row
    const int fr = lane & 15;
    const int q = lane >> 4;
    f32x4 acc[4][4] = {};
    for (int k0 = 0; k0 < K; k0 += 64) {
        __syncthreads();
#pragma unroll
        for (int p = 0; p < 4; ++p) {
            const int row = p * 32 + srow;
            const int sc = (schunk ^ (row & 7)) * 8;
            gload_lds16(&A[(row0 + row) * (long)lda + k0 + sc], As + row * 64 + schunk * 8);
            gload_lds16(&WT[(col0 + row) * (long)K + k0 + sc], Bs + row * 64 + schunk * 8);
        }
        __syncthreads();
#pragma unroll
        for (int kk = 0; kk < 2; ++kk) {
            short8 af[4], bfr[4];
#pragma unroll
            for (int mf = 0; mf < 4; ++mf) {
                const int row = wm * 64 + mf * 16 + fr;
                const int byo = (row * 128 + kk * 64 + q * 16) ^ ((row & 7) << 4);
                af[mf] = *(const short8*)((const char*)As + byo);
            }
#pragma unroll
            for (int nf = 0; nf < 4; ++nf) {
                const int row = wn * 64 + nf * 16 + fr;
                const int byo = (row * 128 + kk * 64 + q * 16) ^ ((row & 7) << 4);
                bfr[nf] = *(const short8*)((const char*)Bs + byo);
            }
#pragma unroll
            for (int mf = 0; mf < 4; ++mf)
#pragma unroll
                for (int nf = 0; nf < 4; ++nf)
                    acc[mf][nf] = __builtin_amdgcn_mfma_f32_16x16x32_bf16(
                        af[mf], bfr[nf], acc[mf][nf], 0, 0, 0);
        }
    }
#pragma unroll
    for (int nf = 0; nf < 4; ++nf) {
        const long col = col0 + wn * 64 + nf * 16 + fr;
        const float bv = bias[col];
#pragma unroll
        for (int mf = 0; mf < 4; ++mf) {
#pragma unroll
            for (int i = 0; i < 4; ++i) {
                const long r = row0 + wm * 64 + mf * 16 + q * 4 + i;
                float vv = acc[mf][nf][i] + bv;
                if (RELU) vv = fmaxf(vv, 0.f);
                if (OUTBF) ((unsigned short*)Cv)[r * ldc + col] = f2b(vv);
                else       ((float*)Cv)[r * ldc + col] = vv;
            }
        }
    }
}

// =====================================================================
// CSR build: edges grouped by global target row tf = g*NN + tgt
// =====================================================================
__global__ void csr_init(int* __restrict__ cnt, int* __restrict__ fill) {
    int gid = blockIdx.x * blockDim.x + threadIdx.x;
    if (gid < NM) { cnt[gid] = 0; fill[gid] = 0; }
}

__global__ void csr_count(const int* __restrict__ eidx, int* __restrict__ cnt) {
    long el = (long)blockIdx.x * blockDim.x + threadIdx.x;
    if (el >= NE) return;
    int g = (int)(el >> 15), e = (int)(el & (EE - 1));
    int tgt = eidx[((long)g * 2 + 1) * EE + e];
    atomicAdd(&cnt[g * NN + tgt], 1);
}

__global__ __launch_bounds__(1024) void csr_scan(const int* __restrict__ cnt, int* __restrict__ off) {
    __shared__ int part[1024];
    const int t = threadIdx.x;
    const int base = t * (NM / 1024);
    int s = 0;
    for (int i = 0; i < NM / 1024; ++i) s += cnt[base + i];
    part[t] = s;
    __syncthreads();
    for (int d = 1; d < 1024; d <<= 1) {
        int v = (t >= d) ? part[t - d] : 0;
        __syncthreads();
        part[t] += v;
        __syncthreads();
    }
    int run = (t == 0) ? 0 : part[t - 1];
    for (int i = 0; i < NM / 1024; ++i) { off[base + i] = run; run += cnt[base + i]; }
    if (t == 1023) off[NM] = run;
}

__global__ void csr_scatter(const int* __restrict__ eidx, const int* __restrict__ off,
                            int* __restrict__ fill, int* __restrict__ csr) {
    long el = (long)blockIdx.x * blockDim.x + threadIdx.x;
    if (el >= NE) return;
    int g = (int)(el >> 15), e = (int)(el & (EE - 1));
    int tgt = eidx[((long)g * 2 + 1) * EE + e];
    int tf = g * NN + tgt;
    int pos = atomicAdd(&fill[tf], 1);
    csr[off[tf] + pos] = (int)el;
}

// =====================================================================
// Fused TransformerConv v3 on interleaved qkv [NM][768].
// 2-edge pairing + 2-pair-ahead prefetch: 4 gathers in flight, two
// independent dot/shfl/exp chains per iteration (sum is associative
// since the plain-exp rewrite). Writes conv output over the q slice.
// =====================================================================
__global__ __launch_bounds__(256) void conv_fused(
    unsigned short* __restrict__ Z,
    const int* __restrict__ eidx, const float* __restrict__ eattr,
    const float* __restrict__ W_edge, const float* __restrict__ b_edge,
    const int* __restrict__ off, const int* __restrict__ csr)
{
    const int tid = threadIdx.x;
    const int wave = tid >> 6, lane = tid & 63;
    const int bid = (blockIdx.x & 7) * (NM / 4 / 8) + (blockIdx.x >> 3);
    const long tf = (long)bid * 4 + wave;
    const int d0 = lane * 4;
    unsigned short* qrow = &Z[tf * 768];
    const ushort4 q4 = *(const ushort4*)&qrow[d0];
    const float q0 = b2f(q4.x), q1 = b2f(q4.y), q2 = b2f(q4.z), q3 = b2f(q4.w);
    const float be0 = b_edge[d0], be1 = b_edge[d0 + 1],
                be2 = b_edge[d0 + 2], be3 = b_edge[d0 + 3];
    float w0[6], w1r[6], w2r[6], w3r[6];
#pragma unroll
    for (int j2 = 0; j2 < 6; ++j2) {
        const float* wp = &W_edge[j2 * 256 + d0];
        w0[j2] = wp[0]; w1r[j2] = wp[1]; w2r[j2] = wp[2]; w3r[j2] = wp[3];
    }
    float qb = q0 * be0 + q1 * be1 + q2 * be2 + q3 * be3;
    float qw[6];
#pragma unroll
    for (int j2 = 0; j2 < 6; ++j2)
        qw[j2] = q0 * w0[j2] + q1 * w1r[j2] + q2 * w2r[j2] + q3 * w3r[j2];
#pragma unroll
    for (int mm = 1; mm <= 4; mm <<= 1) {
        qb += __shfl_xor(qb, mm, 64);
#pragma unroll
        for (int j2 = 0; j2 < 6; ++j2) qw[j2] += __shfl_xor(qw[j2], mm, 64);
    }
    const float scale = 0.17677669529663687f;  // 1/sqrt(32)
    float s = 0.f, a0 = 0.f, a1 = 0.f, a2 = 0.f, a3 = 0.f;
    float t0 = 0.f, t1 = 0.f, t2 = 0.f, t3 = 0.f, t4 = 0.f, t5 = 0.f;
    const int jb = off[tf], je = off[tf + 1];
    const ushort4 zz = {0, 0, 0, 0};
    ushort4 kc0 = zz, vc0 = zz, kc1 = zz, vc1 = zz;
    float ea0[6] = {0.f, 0.f, 0.f, 0.f, 0.f, 0.f};
    float ea1[6] = {0.f, 0.f, 0.f, 0.f, 0.f, 0.f};
    // initial pair load
    if (jb < je) {
        const int el = csr[jb];
        const int g = el >> 15, e = el & (EE - 1);
        const long sf = (long)g * NN + eidx[((long)g * 2) * EE + e];
        kc0 = *(const ushort4*)&Z[sf * 768 + 256 + d0];
        vc0 = *(const ushort4*)&Z[sf * 768 + 512 + d0];
#pragma unroll
        for (int t = 0; t < 6; ++t) ea0[t] = eattr[(long)el * 6 + t];
    }
    if (jb + 1 < je) {
        const int el = csr[jb + 1];
        const int g = el >> 15, e = el & (EE - 1);
        const long sf = (long)g * NN + eidx[((long)g * 2) * EE + e];
        kc1 = *(const ushort4*)&Z[sf * 768 + 256 + d0];
        vc1 = *(const ushort4*)&Z[sf * 768 + 512 + d0];
#pragma unroll
        for (int t = 0; t < 6; ++t) ea1[t] = eattr[(long)el * 6 + t];
    }
    for (int j = jb; j < je; j += 2) {
        ushort4 nk0 = zz, nv0 = zz, nk1 = zz, nv1 = zz;
        float nea0[6] = {0.f, 0.f, 0.f, 0.f, 0.f, 0.f};
        float nea1[6] = {0.f, 0.f, 0.f, 0.f, 0.f, 0.f};
        if (j + 2 < je) {   // prefetch next pair (wave-uniform guards)
            const int el = csr[j + 2];
            const int g = el >> 15, e = el & (EE - 1);
            const long sf = (long)g * NN + eidx[((long)g * 2) * EE + e];
            nk0 = *(const ushort4*)&Z[sf * 768 + 256 + d0];
            nv0 = *(const ushort4*)&Z[sf * 768 + 512 + d0];
#pragma unroll
            for (int t = 0; t < 6; ++t) nea0[t] = eattr[(long)el * 6 + t];
        }
        if (j + 3 < je) {
            const int el = csr[j + 3];
            const int g = el >> 15, e = el & (EE - 1);
            const long sf = (long)g * NN + eidx[((long)g * 2) * EE + e];
            nk1 = *(const ushort4*)&Z[sf * 768 + 256 + d0];
            nv1 = *(const ushort4*)&Z[sf * 768 + 512 + d0];
#pragma unroll
            for (int t = 0; t < 6; ++t) nea1[t] = eattr[(long)el * 6 + t];
        }
        // two independent dot+reduce chains
        float p0 = q0 * b2f(kc0.x) + q1 * b2f(kc0.y) + q2 * b2f(kc0.z) + q3 * b2f(kc0.w);
        float p1 = q0 * b2f(kc1.x) + q1 * b2f(kc1.y) + q2 * b2f(kc1.z) + q3 * b2f(kc1.w);
        p0 += __shfl_xor(p0, 1, 64); p1 += __shfl_xor(p1, 1, 64);
        p0 += __shfl_xor(p0, 2, 64); p1 += __shfl_xor(p1, 2, 64);
        p0 += __shfl_xor(p0, 4, 64); p1 += __shfl_xor(p1, 4, 64);
        float al0 = p0 + qb + ea0[0] * qw[0] + ea0[1] * qw[1] + ea0[2] * qw[2]
                  + ea0[3] * qw[3] + ea0[4] * qw[4] + ea0[5] * qw[5];
        float al1 = p1 + qb + ea1[0] * qw[0] + ea1[1] * qw[1] + ea1[2] * qw[2]
                  + ea1[3] * qw[3] + ea1[4] * qw[4] + ea1[5] * qw[5];
        const float e0 = __expf(al0 * scale);
        const float e1 = (j + 1 < je) ? __expf(al1 * scale) : 0.f;
        s += e0 + e1;
        a0 += e0 * b2f(vc0.x) + e1 * b2f(vc1.x);
        a1 += e0 * b2f(vc0.y) + e1 * b2f(vc1.y);
        a2 += e0 * b2f(vc0.z) + e1 * b2f(vc1.z);
        a3 += e0 * b2f(vc0.w) + e1 * b2f(vc1.w);
        t0 += e0 * ea0[0] + e1 * ea1[0];
        t1 += e0 * ea0[1] + e1 * ea1[1];
        t2 += e0 * ea0[2] + e1 * ea1[2];
        t3 += e0 * ea0[3] + e1 * ea1[3];
        t4 += e0 * ea0[4] + e1 * ea1[4];
        t5 += e0 * ea0[5] + e1 * ea1[5];
        kc0 = nk0; vc0 = nv0; kc1 = nk1; vc1 = nv1;
#pragma unroll
        for (int t = 0; t < 6; ++t) { ea0[t] = nea0[t]; ea1[t] = nea1[t]; }
    }
    const float inv = (s > 0.f) ? 1.f / s : 0.f;
    float o0 = a0 + be0 * s, o1 = a1 + be1 * s, o2 = a2 + be2 * s, o3 = a3 + be3 * s;
    o0 += w0[0]*t0 + w0[1]*t1 + w0[2]*t2 + w0[3]*t3 + w0[4]*t4 + w0[5]*t5;
    o1 += w1r[0]*t0 + w1r[1]*t1 + w1r[2]*t2 + w1r[3]*t3 + w1r[4]*t4 + w1r[5]*t5;
    o2 += w2r[0]*t0 + w2r[1]*t1 + w2r[2]*t2 + w2r[3]*t3 + w2r[4]*t4 + w2r[5]*t5;
    o3 += w3r[0]*t0 + w3r[1]*t1 + w3r[2]*t2 + w3r[3]*t3 + w3r[4]*t4 + w3r[5]*t5;
    ushort4 o;
    o.x = f2b(o0 * inv); o.y = f2b(o1 * inv);
    o.z = f2b(o2 * inv); o.w = f2b(o3 * inv);
    *(ushort4*)&qrow[d0] = o;
}

// seq(bf16, [t*BN+b*N+n][256]) = conv(q-slice of Z) + skip(k-slice of Z)
__global__ void transpose_add(const unsigned short* __restrict__ Z,
                              unsigned short* __restrict__ out) {
    long gid = (long)blockIdx.x * blockDim.x + threadIdx.x;
    long row = gid >> 6;
    int c4 = (int)(gid & 63);
    int n = (int)(row % NN);
    int bt = (int)(row / NN);
    int t = bt % TT, b = bt / TT;
    long orow = (long)t * BN + (long)b * NN + n;
    ushort4 cv = ((const ushort4*)&Z[row * 768])[c4];
    ushort4 sv = ((const ushort4*)&Z[row * 768 + 256])[c4];
    ushort4 o;
    o.x = f2b(b2f(cv.x) + b2f(sv.x));
    o.y = f2b(b2f(cv.y) + b2f(sv.y));
    o.z = f2b(b2f(cv.z) + b2f(sv.z));
    o.w = f2b(b2f(cv.w) + b2f(sv.w));
    ((ushort4*)out)[orow * 64 + c4] = o;
}

// temporal attention over T=5 on interleaved qkv [NM][768]; o over q-slice.
__global__ __launch_bounds__(256) void mha_time(unsigned short* __restrict__ Z)
{
    const int tid = threadIdx.x;
    const int grp = tid >> 5, c = tid & 31;
    long pair = (long)blockIdx.x * 8 + grp;
    int h = (int)(pair & 7);
    long bn = pair >> 3;
    const float scale = 0.17677669529663687f;
    float qv[TT], kv[TT], vv[TT];
    long r[TT];
#pragma unroll
    for (int t = 0; t < TT; ++t) {
        r[t] = ((long)t * BN + bn) * 768 + h * 32 + c;
        qv[t] = b2f(Z[r[t]]); kv[t] = b2f(Z[r[t] + 256]); vv[t] = b2f(Z[r[t] + 512]);
    }
    float s[TT][TT];
#pragma unroll
    for (int t = 0; t < TT; ++t)
#pragma unroll
        for (int u = 0; u < TT; ++u) {
            float p = qv[t] * kv[u];
#pragma unroll
            for (int m = 16; m >= 1; m >>= 1) p += __shfl_xor(p, m, 64);
            s[t][u] = p * scale;
        }
#pragma unroll
    for (int t = 0; t < TT; ++t) {
        float mx = s[t][0];
#pragma unroll
        for (int u = 1; u < TT; ++u) mx = fmaxf(mx, s[t][u]);
        float sm = 0.f;
#pragma unroll
        for (int u = 0; u < TT; ++u) { s[t][u] = expf(s[t][u] - mx); sm += s[t][u]; }
        float inv = 1.f / sm;
        float o = 0.f;
#pragma unroll
        for (int u = 0; u < TT; ++u) o += s[t][u] * vv[u];
        Z[r[t]] = f2b(o * inv);
    }
}

// seq(bf16) = LayerNorm(seq + res(bf16, row-stride rstride)) * g + b
__global__ __launch_bounds__(256) void ln_residual(
    unsigned short* __restrict__ seq, const unsigned short* __restrict__ res,
    int rstride, const float* __restrict__ g, const float* __restrict__ b)
{
    const int wave = threadIdx.x >> 6, lane = threadIdx.x & 63;
    long row = (long)blockIdx.x * 4 + wave;
    const ushort4 s4 = *(const ushort4*)&seq[row * 256 + lane * 4];
    const ushort4 r4 = *(const ushort4*)&res[row * (long)rstride + lane * 4];
    float x[4] = { b2f(s4.x) + b2f(r4.x), b2f(s4.y) + b2f(r4.y),
                   b2f(s4.z) + b2f(r4.z), b2f(s4.w) + b2f(r4.w) };
    float sum = x[0] + x[1] + x[2] + x[3];
#pragma unroll
    for (int m = 32; m >= 1; m >>= 1) sum += __shfl_xor(sum, m, 64);
    float mean = sum * (1.f / 256.f);
    float vs = 0.f;
#pragma unroll
    for (int i = 0; i < 4; ++i) { float dl = x[i] - mean; vs += dl * dl; }
#pragma unroll
    for (int m = 32; m >= 1; m >>= 1) vs += __shfl_xor(vs, m, 64);
    float inv = rsqrtf(vs * (1.f / 256.f) + 1e-5f);
    ushort4 o;
    o.x = f2b((x[0] - mean) * inv * g[lane * 4 + 0] + b[lane * 4 + 0]);
    o.y = f2b((x[1] - mean) * inv * g[lane * 4 + 1] + b[lane * 4 + 1]);
    o.z = f2b((x[2] - mean) * inv * g[lane * 4 + 2] + b[lane * 4 + 2]);
    o.w = f2b((x[3] - mean) * inv * g[lane * 4 + 3] + b[lane * 4 + 3]);
    *(ushort4*)&seq[row * 256 + lane * 4] = o;
}

// out[row][0..9] = seq[t=T-1 rows](bf16) @ W_out + b_out ; one block per row
__global__ __launch_bounds__(256) void final_out(
    const unsigned short* __restrict__ seq, const float* __restrict__ Wd,
    const float* __restrict__ bd, float* __restrict__ out)
{
    __shared__ float xs[256];
    long row = blockIdx.x;
    xs[threadIdx.x] = b2f(seq[((long)(TT - 1) * BN + row) * 256 + threadIdx.x]);
    __syncthreads();
    const int wv = threadIdx.x >> 6, lane = threadIdx.x & 63;
    for (int o = wv; o < NCLS; o += 4) {
        float p = 0.f;
#pragma unroll
        for (int i = 0; i < 4; ++i) {
            int kk = lane + 64 * i;
            p += xs[kk] * Wd[kk * NCLS + o];
        }
#pragma unroll
        for (int m = 32; m >= 1; m >>= 1) p += __shfl_xor(p, m, 64);
        if (lane == 0) out[row * NCLS + o] = p + bd[o];
    }
}

__global__ void fill_sentinel(float* __restrict__ out, int n) {
    int gid = blockIdx.x * blockDim.x + threadIdx.x;
    if (gid < n) out[gid] = 1.0e6f;
}

// =====================================================================
extern "C" void kernel_launch(void* const* d_in, const int* in_sizes, int n_in,
                              void* d_out, int out_size, void* d_ws, size_t ws_size,
                              hipStream_t stream) {
    const float* xseq  = (const float*)d_in[0];
    const int*   eidx  = (const int*)d_in[1];
    const float* eattr = (const float*)d_in[2];
    const float* W_node = (const float*)d_in[3];
    const float* b_node = (const float*)d_in[4];
    const float* W_edge = (const float*)d_in[5];
    const float* b_edge = (const float*)d_in[6];
    const float* Wq = (const float*)d_in[7];  const float* bq = (const float*)d_in[8];
    const float* Wk = (const float*)d_in[9];  const float* bk = (const float*)d_in[10];
    const float* Wv = (const float*)d_in[11]; const float* bv = (const float*)d_in[12];
    const float* Ws = (const float*)d_in[13]; const float* bs = (const float*)d_in[14];
    const float* Wqkv = (const float*)d_in[15]; const float* bqkv = (const float*)d_in[16];
    const float* Wo = (const float*)d_in[17];   const float* bo = (const float*)d_in[18];
    const float* W1 = (const float*)d_in[19];   const float* b1 = (const float*)d_in[20];
    const float* W2 = (const float*)d_in[21];   const float* b2 = (const float*)d_in[22];
    const float* g_ln1 = (const float*)d_in[23]; const float* b_ln1 = (const float*)d_in[24];
    const float* g_ln2 = (const float*)d_in[25]; const float* b_ln2 = (const float*)d_in[26];
    const float* W_out = (const float*)d_in[27]; const float* b_out = (const float*)d_in[28];
    float* out = (float*)d_out;

    // ---- workspace layout ----
    const long SZ = (long)NM * DD;            // 20,971,520 elements
    unsigned short* Abf = (unsigned short*)d_ws;     // seq activations bf16 (40MB)
    unsigned short* Zu  = Abf + SZ;                  // qkv interleaved [NM][768] (120MB)
    unsigned short* Hid = Zu;                        // FFN hidden bf16 [MR][2048] (64MB)
    unsigned short* res2B = Zu + (long)MR * FFD;     // FFN residual bf16 [MR][256] (8MB)
    unsigned short* WX = Zu + 3 * SZ;
    unsigned short* xbf = WX;                             // 81920*64
    unsigned short* wtN = xbf + (long)NM * FIN;           // [256][64]
    unsigned short* wtQ = wtN + 256 * 64;                 // [768][256] stacked q,k,v
    unsigned short* wtK = wtQ + 65536;
    unsigned short* wtV = wtK + 65536;
    unsigned short* wtS = wtV + 65536;
    unsigned short* wtQKV = wtS + 65536;                  // 3 * [768][256]
    unsigned short* wtO = wtQKV + 3L * 768 * 256;         // 3 * [256][256]
    unsigned short* wtW1 = wtO + 3L * 65536;              // 3 * [2048][256]
    unsigned short* wtW2 = wtW1 + 3L * 2048 * 256;        // 3 * [256][2048]
    int* cnt  = (int*)(wtW2 + 3L * 256 * 2048);
    int* coff = cnt + NM;                                 // NM+1
    int* cfil = coff + NM + 1;
    int* csr  = cfil + NM;                                // NE ints
    float* qkvb = (float*)(csr + NE);                     // 768 packed bias
    char* wend = (char*)(qkvb + 768);
    const size_t need = (size_t)(wend - (char*)d_ws);
    if (ws_size < need) {
        fill_sentinel<<<dim3((out_size + 255) / 256), dim3(256), 0, stream>>>(out, out_size);
        return;
    }

    dim3 blk(256);
    dim3 tb(32, 8);

    // ---- prologue ----
    xconvert<<<dim3((unsigned)((long)NM * FIN / 4 / 256)), blk, 0, stream>>>(xseq, xbf, (long)NM * FIN / 4);
    wtrans<<<dim3(DD / 32, FIN / 32), tb, 0, stream>>>(W_node, wtN, FIN, DD);
    wtrans<<<dim3(DD / 32, DD / 32), tb, 0, stream>>>(Wq, wtQ, DD, DD);
    wtrans<<<dim3(DD / 32, DD / 32), tb, 0, stream>>>(Wk, wtK, DD, DD);
    wtrans<<<dim3(DD / 32, DD / 32), tb, 0, stream>>>(Wv, wtV, DD, DD);
    wtrans<<<dim3(DD / 32, DD / 32), tb, 0, stream>>>(Ws, wtS, DD, DD);
    pack3<<<dim3(1), blk, 0, stream>>>(bq, bk, bv, qkvb);
    for (int l = 0; l < 3; ++l) {
        wtrans<<<dim3(768 / 32, DD / 32), tb, 0, stream>>>(Wqkv + (long)l * DD * 768, wtQKV + (long)l * 768 * 256, DD, 768);
        wtrans<<<dim3(DD / 32, DD / 32), tb, 0, stream>>>(Wo + (long)l * DD * DD, wtO + (long)l * 65536, DD, DD);
        wtrans<<<dim3(FFD / 32, DD / 32), tb, 0, stream>>>(W1 + (long)l * DD * FFD, wtW1 + (long)l * 2048 * 256, DD, FFD);
        wtrans<<<dim3(DD / 32, FFD / 32), tb, 0, stream>>>(W2 + (long)l * FFD * DD, wtW2 + (long)l * 256 * 2048, FFD, DD);
    }

    // ---- CSR build ----
    csr_init<<<dim3((NM + 255) / 256), blk, 0, stream>>>(cnt, cfil);
    csr_count<<<dim3((unsigned)(NE / 256)), blk, 0, stream>>>(eidx, cnt);
    csr_scan<<<dim3(1), dim3(1024), 0, stream>>>(cnt, coff);
    csr_scatter<<<dim3((unsigned)(NE / 256)), blk, 0, stream>>>(eidx, coff, cfil, csr);

    // ---- stage 1 ----
    gemm_mfma<false, true><<<dim3(NM / 128, DD / 128), blk, 0, stream>>>(
        xbf, FIN, wtN, b_node, Abf, DD, FIN);
    gemm_mfma<false, true><<<dim3(NM / 128, 768 / 128), blk, 0, stream>>>(
        Abf, DD, wtQ, qkvb, Zu, 768, DD);
    conv_fused<<<dim3(NM / 4), blk, 0, stream>>>(
        Zu, eidx, eattr, W_edge, b_edge, coff, csr);
    gemm_mfma<false, true><<<dim3(NM / 128, DD / 128), blk, 0, stream>>>(
        Abf, DD, wtS, bs, (void*)(Zu + 256), 768, DD);
    transpose_add<<<dim3(NM * 64 / 256), blk, 0, stream>>>(Zu, Abf);

    // ---- stage 2: 3 temporal transformer encoder layers ----
    for (int l = 0; l < 3; ++l) {
        gemm_mfma<false, true><<<dim3(NM / 128, 768 / 128), blk, 0, stream>>>(
            Abf, DD, wtQKV + (long)l * 768 * 256, bqkv + (long)l * 768, Zu, 768, DD);
        mha_time<<<dim3(BN * HH / 8), blk, 0, stream>>>(Zu);
        gemm_mfma<false, true><<<dim3(NM / 128, DD / 128), blk, 0, stream>>>(
            Zu, 768, wtO + (long)l * 65536, bo + (long)l * DD, (void*)(Zu + 512), 768, DD);
        ln_residual<<<dim3(NM / 4), blk, 0, stream>>>(
            Abf, Zu + 512, 768, g_ln1 + l * DD, b_ln1 + l * DD);
        // unfused FFN (register-pressure-safe), hidden in Zu region
        for (int mr = 0; mr < NM / MR; ++mr) {
            const long r0 = (long)mr * MR;
            gemm_mfma<true, true><<<dim3(MR / 128, FFD / 128), blk, 0, stream>>>(
                Abf + r0 * DD, DD, wtW1 + (long)l * 2048 * 256, b1 + (long)l * FFD, Hid, FFD, DD);
            gemm_mfma<false, true><<<dim3(MR / 128, DD / 128), blk, 0, stream>>>(
                Hid, FFD, wtW2 + (long)l * 256 * 2048, b2 + (long)l * DD, res2B, DD, FFD);
            ln_residual<<<dim3(MR / 4), blk, 0, stream>>>(
                Abf + r0 * DD, res2B, DD, g_ln2 + l * DD, b_ln2 + l * DD);
        }
    }

    // ---- output head ----
    final_out<<<dim3(BN), blk, 0, stream>>>(Abf, W_out, b_out, out);
}